// Round 13
// baseline (245.948 us; speedup 1.0000x reference)
//
#include <hip/hip_runtime.h>
#include <math.h>

#define BSZ 64
#define NPT 16384
#define SEG 16
#define NFPS 256
#define MAXPTS 2048
#define NLANES 64

typedef __attribute__((ext_vector_type(2))) float f32x2;

// Fused packed-f32 squared distance for one pair of points:
// d = (dx*dx + dy*dy) + dz*dz, per-element IEEE rn, no FMA — the exact
// instruction sequence of the reference, one asm block so the compiler
// doesn't insert boundary v_movs between 8 separate asm statements.
__device__ __forceinline__ f32x2 dist_pair(f32x2 x, f32x2 y, f32x2 z,
                                           f32x2 ncx, f32x2 ncy, f32x2 ncz) {
    f32x2 d, t0, t1;
    asm("v_pk_add_f32 %1, %3, %6\n\t"   // t0 = x + (-cx)   == dx
        "v_pk_add_f32 %2, %4, %7\n\t"   // t1 = y + (-cy)   == dy
        "v_pk_mul_f32 %0, %1, %1\n\t"   // d  = dx*dx
        "v_pk_mul_f32 %2, %2, %2\n\t"   // t1 = dy*dy
        "v_pk_add_f32 %0, %0, %2\n\t"   // d  = dx*dx + dy*dy
        "v_pk_add_f32 %1, %5, %8\n\t"   // t0 = z + (-cz)   == dz
        "v_pk_mul_f32 %1, %1, %1\n\t"   // t0 = dz*dz
        "v_pk_add_f32 %0, %0, %1"       // d  = (dx*dx+dy*dy) + dz*dz
        : "=&v"(d), "=&v"(t0), "=&v"(t1)
        : "v"(x), "v"(y), "v"(z), "v"(ncx), "v"(ncy), "v"(ncz));
    return d;
}

// u64 max with DPP-shifted partner (reduce-to-lane63). bound_ctrl=1 shifts in
// 0 == identity (keys >= 0: hi word is positive-float bits). Proven in R3/R12.
template <int CTRL>
__device__ __forceinline__ unsigned long long dpp_max_u64(unsigned long long k) {
    const int lo = __builtin_amdgcn_update_dpp(0, (int)(unsigned)k, CTRL, 0xf, 0xf, true);
    const int hi = __builtin_amdgcn_update_dpp(0, (int)(unsigned)(k >> 32), CTRL, 0xf, 0xf, true);
    const unsigned long long ok = ((unsigned long long)(unsigned)hi << 32) | (unsigned)lo;
    return ok > k ? ok : k;
}

// Phase 2 with compile-time pair count P (covers count <= 128*P; pads -inf).
template <int P>
__device__ __forceinline__ void fps_phase2(const float4* __restrict__ pts,
                                           float* __restrict__ out,
                                           size_t gp_base, int count, int lane) {
    f32x2 xp[P], yp[P], zp[P];
    float md[2 * P];
    #pragma unroll
    for (int p = 0; p < P; ++p) {
        const int i0 = (2 * p) * NLANES + lane;
        const int i1 = i0 + NLANES;
        const bool v0 = (i0 < count), v1 = (i1 < count);
        const float4 q0 = pts[v0 ? i0 : 0];
        const float4 q1 = pts[v1 ? i1 : 0];
        xp[p].x = q0.x; xp[p].y = q1.x;
        yp[p].x = q0.y; yp[p].y = q1.y;
        zp[p].x = q0.z; zp[p].y = q1.z;
        md[2 * p]     = v0 ? INFINITY : -INFINITY;
        md[2 * p + 1] = v1 ? INFINITY : -INFINITY;
    }

    float4 c = pts[0];          // first masked point == argmax(mask)
    float scx[4], scy[4], scz[4];  // selected-point register banks (t = c4*64+lane)

    #pragma unroll
    for (int c4 = 0; c4 < 4; ++c4) {
        for (int tt = 0; tt < 64; ++tt) {
            // save this iteration's cur_pt into bank c4 on lane tt (no global store)
            const bool mine = (lane == tt);
            scx[c4] = mine ? c.x : scx[c4];
            scy[c4] = mine ? c.y : scy[c4];
            scz[c4] = mine ? c.z : scz[c4];

            f32x2 ncx; ncx.x = -c.x; ncx.y = -c.x;
            f32x2 ncy; ncy.x = -c.y; ncy.y = -c.y;
            f32x2 ncz; ncz.x = -c.z; ncz.y = -c.z;

            // 4 (value,slot) tracking chains. Slots 0..3 always valid
            // (count>=256) -> every chain ends finite non-negative; strict >
            // keeps the lowest slot within each chain.
            float bv0 = -INFINITY, bv1 = -INFINITY, bv2 = -INFINITY, bv3 = -INFINITY;
            int bs0 = 0, bs1 = 0, bs2 = 0, bs3 = 0;
            #pragma unroll
            for (int p = 0; p < P; ++p) {
                const f32x2 d = dist_pair(xp[p], yp[p], zp[p], ncx, ncy, ncz);
                const float m0 = fminf(md[2 * p], d.x);
                const float m1 = fminf(md[2 * p + 1], d.y);
                md[2 * p] = m0;
                md[2 * p + 1] = m1;
                if (p & 1) {
                    if (m0 > bv2) { bv2 = m0; bs2 = 2 * p; }
                    if (m1 > bv3) { bv3 = m1; bs3 = 2 * p + 1; }
                } else {
                    if (m0 > bv0) { bv0 = m0; bs0 = 2 * p; }
                    if (m1 > bv1) { bv1 = m1; bs1 = 2 * p + 1; }
                }
            }

            // Pack u64 keys: (value_bits << 32) | ~(slot*64+lane).
            // u64 max == (max value, min compacted idx) == np.argmax first-max.
            const unsigned lo0 = ~(unsigned)((bs0 << 6) | lane);
            const unsigned lo1 = ~(unsigned)((bs1 << 6) | lane);
            const unsigned lo2 = ~(unsigned)((bs2 << 6) | lane);
            const unsigned lo3 = ~(unsigned)((bs3 << 6) | lane);
            unsigned long long k0 = ((unsigned long long)__float_as_uint(bv0) << 32) | lo0;
            const unsigned long long k1 = ((unsigned long long)__float_as_uint(bv1) << 32) | lo1;
            unsigned long long k2 = ((unsigned long long)__float_as_uint(bv2) << 32) | lo2;
            const unsigned long long k3 = ((unsigned long long)__float_as_uint(bv3) << 32) | lo3;
            if (k1 > k0) k0 = k1;
            if (k3 > k2) k2 = k3;
            unsigned long long key = (k2 > k0) ? k2 : k0;

            // wave64 u64 max reduce to lane 63 (DPP; lo/hi movs independent)
            key = dpp_max_u64<0x111>(key);  // row_shr:1
            key = dpp_max_u64<0x112>(key);  // row_shr:2
            key = dpp_max_u64<0x114>(key);  // row_shr:4
            key = dpp_max_u64<0x118>(key);  // row_shr:8
            key = dpp_max_u64<0x142>(key);  // row_bcast:15
            key = dpp_max_u64<0x143>(key);  // row_bcast:31

            // single scalar round-trip: one readlane -> uniform idx -> LDS bcast
            const unsigned keylo =
                (unsigned)__builtin_amdgcn_readlane((int)(unsigned)key, 63);
            const int idx = (int)(~keylo);
            c = pts[idx];               // uniform-addr ds_read_b128 broadcast
        }
    }

    // batched output: 12 stores per lane, once
    #pragma unroll
    for (int c4 = 0; c4 < 4; ++c4) {
        const size_t o = gp_base + (size_t)(c4 * 64 + lane) * 3;
        out[o + 0] = scx[c4];
        out[o + 1] = scy[c4];
        out[o + 2] = scz[c4];
    }
}

__global__ __launch_bounds__(NLANES, 1) void fps_part_kernel(const float* __restrict__ x,
                                                             float* __restrict__ out) {
    // XCD swizzle: all 16 segment-blocks of one batch share blockIdx%8 -> same
    // XCD L2 caches that batch's 256KB slice once (8 batches/XCD = 2MB < 4MB L2).
    const int blk = blockIdx.x;
    const int xcd = blk & 7;
    const int grp = blk >> 3;            // 0..127
    const int b = (xcd << 3) | (grp >> 4);
    const int s = grp & 15;
    const int prob = b * SEG + s;        // logical problem id (output slot)
    const int lane = threadIdx.x;        // single wave

    __shared__ float4 pts[MAXPTS];

    // ---------------- Phase 1: stable compaction (wave-coherent, no barriers) ----------------
    const float4* x4 = (const float4*)x + (size_t)b * NPT;
    const float fs = (float)s;
    const unsigned long long lanemask = (1ull << lane) - 1ull;
    int total = 0;

    for (int mc = 0; mc < 32; ++mc) {
        float4 p[8];
        #pragma unroll
        for (int j = 0; j < 8; ++j)
            p[j] = x4[(mc * 8 + j) * NLANES + lane];
        #pragma unroll
        for (int j = 0; j < 8; ++j) {
            const bool pred = (p[j].w == fs);
            const unsigned long long m = __ballot(pred);
            const int pos = total + __popcll(m & lanemask);
            if (pred && pos < MAXPTS) pts[pos] = p[j];
            total += __popcll(m);   // uniform -> SALU
        }
    }
    __syncthreads();  // single wave: cheap; orders ds_writes before ds_reads

    const int count = (total < MAXPTS) ? total : MAXPTS;
    const size_t gp_base = (size_t)prob * NFPS * 3;
    const size_t mask_off = (size_t)BSZ * SEG * NFPS * 3 + (size_t)prob;

    if (count < NFPS) {
        for (int i = lane; i < NFPS * 3; i += NLANES) out[gp_base + i] = 0.0f;
        if (lane == 0) out[mask_off] = 0.0f;
        return;
    }
    if (lane == 0) out[mask_off] = 1.0f;

    // ---------------- Phase 2: compile-time-specialized pair count ----------------
    const int cnt_s = __builtin_amdgcn_readfirstlane(count);
    const int pmax = (cnt_s + 127) >> 7;   // ceil(count/128); ~8-9 for count~1024

    if (pmax <= 8)       fps_phase2<8>(pts, out, gp_base, count, lane);
    else if (pmax == 9)  fps_phase2<9>(pts, out, gp_base, count, lane);
    else                 fps_phase2<16>(pts, out, gp_base, count, lane);
}

extern "C" void kernel_launch(void* const* d_in, const int* in_sizes, int n_in,
                              void* d_out, int out_size, void* d_ws, size_t ws_size,
                              hipStream_t stream) {
    const float* x = (const float*)d_in[0];
    float* out = (float*)d_out;
    fps_part_kernel<<<BSZ * SEG, NLANES, 0, stream>>>(x, out);
}